// Round 9
// baseline (556.333 us; speedup 1.0000x reference)
//
#include <hip/hip_runtime.h>
#include <hip/hip_bf16.h>

#define S_LEN 2048
#define HID_D 2048
#define NHEAD 16
#define QLORA 1536
#define KVLORA 512
#define DNOPE 128
#define DROPE 64
#define DV 128
#define DQK 192
#define CKV_PAD 640  // KVLORA+DROPE (576) padded to x128

typedef __hip_bfloat16 bf16;
typedef __attribute__((ext_vector_type(8))) short short8;
typedef __attribute__((ext_vector_type(4))) float f32x4;

__device__ __forceinline__ float ldE(const float* p) { return *p; }
__device__ __forceinline__ float ldE(const bf16* p) { return __bfloat162float(*p); }
__device__ __forceinline__ void stE(float* p, float v) { *p = v; }
__device__ __forceinline__ void stE(bf16* p, float v) { *p = __float2bfloat16(v); }

__device__ __forceinline__ short bf16bits(float v) {
    __hip_bfloat16 h = __float2bfloat16(v);
    return *reinterpret_cast<short*>(&h);
}

__device__ __forceinline__ f32x4 mfma16(short8 a, short8 b, f32x4 c) {
    return __builtin_amdgcn_mfma_f32_16x16x32_bf16(a, b, c, 0, 0, 0);
}

// async global->LDS, 16B/lane. LDS dest = wave-uniform base + lane*16 (HW adds it).
__device__ __forceinline__ void gload16(const void* g, void* l) {
    __builtin_amdgcn_global_load_lds(
        (const __attribute__((address_space(1))) unsigned int*)g,
        (__attribute__((address_space(3))) unsigned int*)l, 16, 0, 0);
}

// Detect fp32 vs bf16 inputs by sniffing `hidden` as bf16 (parallel, 256 thr).
__global__ void detect_kernel(const void* hidden, int* flag) {
    __shared__ int red[256];
    const int tid = threadIdx.x;
    const bf16* hb = (const bf16*)hidden;
    float a = fabsf(__bfloat162float(hb[tid]));
    red[tid] = (!(a < 64.f) || (a != 0.f && a < 1e-30f)) ? 1 : 0;
    __syncthreads();
    for (int o = 128; o > 0; o >>= 1) {
        if (tid < o) red[tid] += red[tid + o];
        __syncthreads();
    }
    if (tid == 0) *flag = (red[0] > 16) ? 1 : 0;  // 1 => fp32
}

// out[i] = bf16(in[i]), 8 elems/thread.
__global__ void convert_kernel(const void* in, bf16* out, int n8, const int* flag) {
    int i = blockIdx.x * 256 + threadIdx.x;
    if (i >= n8) return;
    size_t off = (size_t)i * 8;
    short8 o;
    if (*flag) {
        const float* f = (const float*)in + off;
#pragma unroll
        for (int j = 0; j < 8; ++j) o[j] = bf16bits(f[j]);
    } else {
        o = *(const short8*)((const short*)in + off);
    }
    *(short8*)((short*)out + off) = o;
}

// out[Npad][K] (bf16) = in[K][N]^T, zero rows n>=N. K%64==0, N%64==0, Npad%64==0.
__global__ void transpose_kernel(const void* in, bf16* out, int K, int N, int Npad,
                                 const int* flag) {
    __shared__ __align__(16) short Ts[64][80];
    const int tid = threadIdx.x;
    const int n0 = blockIdx.x * 64, k0 = blockIdx.y * 64;
    const bool inb = n0 < N;  // tiles fully in or fully out (N%64==0)
    const int fp32 = *flag;
    const int kl = tid >> 4;
    const int nl = (tid & 15) * 4;
#pragma unroll
    for (int p = 0; p < 4; ++p) {
        int k = kl + p * 16;
        float v[4] = {0.f, 0.f, 0.f, 0.f};
        if (inb) {
            if (fp32) {
                const float4 f = *(const float4*)((const float*)in + (size_t)(k0 + k) * N + n0 + nl);
                v[0] = f.x; v[1] = f.y; v[2] = f.z; v[3] = f.w;
            } else {
                const bf16* bp = (const bf16*)in + (size_t)(k0 + k) * N + n0 + nl;
#pragma unroll
                for (int i = 0; i < 4; ++i) v[i] = __bfloat162float(bp[i]);
            }
        }
#pragma unroll
        for (int i = 0; i < 4; ++i) Ts[nl + i][k] = bf16bits(v[i]);
    }
    __syncthreads();
    const int nr = tid >> 2;
    const int kq = (tid & 3) * 16;
    short* op = (short*)out + (size_t)(n0 + nr) * K + k0 + kq;
    *(short8*)op = *(short8*)&Ts[nr][kq];
    *(short8*)(op + 8) = *(short8*)&Ts[nr][kq + 8];
}

// C[M][N] = A[M][K] @ Bt[N][K]^T, bf16 in, fp32 acc. 128x128 tile, BK=32,
// 4 waves 2x2, each 64x64 = 4x4 mfma_16x16x32. global_load_lds width-16 staging
// with k-quad XOR swizzle (slot = kq ^ ((row>>1)&3)): frag ds_read_b128 conflict-free.
template <typename TC>
__device__ void mgemm_body(const bf16* __restrict__ A, const bf16* __restrict__ Bt,
                           TC* __restrict__ C, int M, int N, int K) {
    __shared__ __align__(16) short As[128 * 32];
    __shared__ __align__(16) short Bs[128 * 32];
    const int tid = threadIdx.x;
    const int w = tid >> 6, lane = tid & 63;
    const int lg = lane >> 4, ln = lane & 15;
    const int wm = w >> 1, wn = w & 1;
    const int m0 = blockIdx.y * 128, n0 = blockIdx.x * 128;

    const int c0 = w * 128 + lane, c1 = c0 + 64;
    const int r0 = c0 >> 2, kq0 = (c0 & 3) ^ ((r0 >> 1) & 3);
    const int r1 = c1 >> 2, kq1 = (c1 & 3) ^ ((r1 >> 1) & 3);
    const bf16* aP0 = A + (size_t)(m0 + r0) * K + kq0 * 8;
    const bf16* aP1 = A + (size_t)(m0 + r1) * K + kq1 * 8;
    const bf16* bP0 = Bt + (size_t)(n0 + r0) * K + kq0 * 8;
    const bf16* bP1 = Bt + (size_t)(n0 + r1) * K + kq1 * 8;
    short* aL0 = As + (size_t)(w * 128) * 8;  // wave-uniform LDS bases
    short* aL1 = As + (size_t)(w * 128 + 64) * 8;
    short* bL0 = Bs + (size_t)(w * 128) * 8;
    short* bL1 = Bs + (size_t)(w * 128 + 64) * 8;

    const int sx = lg ^ ((ln >> 1) & 3);
    int aoff[4], boff[4];
#pragma unroll
    for (int i = 0; i < 4; ++i) {
        aoff[i] = (wm * 64 + i * 16 + ln) * 32 + sx * 8;
        boff[i] = (wn * 64 + i * 16 + ln) * 32 + sx * 8;
    }

    f32x4 acc[4][4];
#pragma unroll
    for (int i = 0; i < 4; ++i)
#pragma unroll
        for (int j = 0; j < 4; ++j) acc[i][j] = (f32x4){0.f, 0.f, 0.f, 0.f};

    for (int k0 = 0; k0 < K; k0 += 32) {
        __syncthreads();
        gload16(aP0 + k0, aL0);
        gload16(aP1 + k0, aL1);
        gload16(bP0 + k0, bL0);
        gload16(bP1 + k0, bL1);
        __syncthreads();
        short8 af[4], bfr[4];
#pragma unroll
        for (int i = 0; i < 4; ++i) af[i] = *(const short8*)&As[aoff[i]];
#pragma unroll
        for (int j = 0; j < 4; ++j) bfr[j] = *(const short8*)&Bs[boff[j]];
#pragma unroll
        for (int i = 0; i < 4; ++i)
#pragma unroll
            for (int j = 0; j < 4; ++j) acc[i][j] = mfma16(af[i], bfr[j], acc[i][j]);
    }
#pragma unroll
    for (int i = 0; i < 4; ++i)
#pragma unroll
        for (int j = 0; j < 4; ++j) {
            TC* cp = C + (size_t)(m0 + wm * 64 + i * 16 + lg * 4) * N + n0 + wn * 64 + j * 16 + ln;
#pragma unroll
            for (int r = 0; r < 4; ++r)
                stE(cp + (size_t)r * N, acc[i][j][r]);
        }
}

// FINAL=1: C=d_out (fp32 when flag, else bf16). FINAL=0: C=ws bf16.
template <int FINAL>
__global__ __launch_bounds__(256, 2)
void mgemm_kernel(const bf16* A, const bf16* Bt, void* C, int M, int N, int K,
                  const int* flag) {
    if (FINAL && *flag) mgemm_body<float>(A, Bt, (float*)C, M, N, K);
    else                mgemm_body<bf16>(A, Bt, (bf16*)C, M, N, K);
}

template <typename TG>
__device__ void rmsnorm_body(const bf16* __restrict__ x, const TG* __restrict__ g,
                             bf16* __restrict__ y, int len, int xstride, int ystride) {
    const int s = blockIdx.x;
    const int tid = threadIdx.x;
    const bf16* xr = x + (size_t)s * xstride;
    float ss = 0.f;
    for (int i = tid; i < len; i += 256) {
        float v = __bfloat162float(xr[i]);
        ss += v * v;
    }
    __shared__ float red[256];
    red[tid] = ss;
    __syncthreads();
    for (int o = 128; o > 0; o >>= 1) {
        if (tid < o) red[tid] += red[tid + o];
        __syncthreads();
    }
    const float scale = rsqrtf(red[0] / (float)len + 1e-6f);
    bf16* yr = y + (size_t)s * ystride;
    for (int i = tid; i < len; i += 256)
        yr[i] = __float2bfloat16(__bfloat162float(xr[i]) * scale * ldE(&g[i]));
}

__global__ void rmsnorm_kernel(const bf16* x, const void* g, bf16* y,
                               int len, int xstride, int ystride, const int* flag) {
    if (*flag) rmsnorm_body<float>(x, (const float*)g, y, len, xstride, ystride);
    else       rmsnorm_body<bf16>(x, (const bf16*)g, y, len, xstride, ystride);
}

// RoPE (deinterleave form): out[p] = x[2p]*c - x[2p+1]*s; out[p+32] = x[2p+1]*c + x[2p]*s.
template <typename TG>
__device__ void rope_body(bf16* __restrict__ q, const bf16* __restrict__ ckv,
                          bf16* __restrict__ kpe, const TG* __restrict__ cosb,
                          const TG* __restrict__ sinb) {
    const int s = blockIdx.x;
    const int tid = threadIdx.x;  // blockDim = 576
    float x0 = 0.f, x1 = 0.f, c = 0.f, sn = 0.f;
    bf16* qbase = nullptr;
    int p = 0;
    const bool isq = tid < 512;
    const bool active = tid < 544;
    if (active) {
        if (isq) {
            const int h = tid >> 5;
            p = tid & 31;
            qbase = q + (size_t)s * (NHEAD * DQK) + h * DQK + DNOPE;
            x0 = __bfloat162float(qbase[2 * p]);
            x1 = __bfloat162float(qbase[2 * p + 1]);
        } else {
            p = tid - 512;
            const bf16* kb = ckv + (size_t)s * CKV_PAD + KVLORA;
            x0 = __bfloat162float(kb[2 * p]);
            x1 = __bfloat162float(kb[2 * p + 1]);
        }
        c = ldE(&cosb[s * 64 + p]);
        sn = ldE(&sinb[s * 64 + p]);
    }
    __syncthreads();
    if (active) {
        if (isq) {
            qbase[p] = __float2bfloat16(x0 * c - x1 * sn);
            qbase[p + 32] = __float2bfloat16(x1 * c + x0 * sn);
        } else {
            kpe[s * 64 + p] = __float2bfloat16(x0 * c - x1 * sn);
            kpe[s * 64 + p + 32] = __float2bfloat16(x1 * c + x0 * sn);
        }
    }
}

__global__ void rope_kernel(bf16* q, const bf16* ckv, bf16* kpe,
                            const void* cosb, const void* sinb, const int* flag) {
    if (*flag) rope_body<float>(q, ckv, kpe, (const float*)cosb, (const float*)sinb);
    else       rope_body<bf16>(q, ckv, kpe, (const bf16*)cosb, (const bf16*)sinb);
}

// Flash-style MFMA attention with REGISTER PREFETCH: tile t+1's global loads are
// issued right after tile t's LDS writes and complete under tile t's compute.
// Staging index math is byte-identical to the round-7/8-verified version.
__global__ __launch_bounds__(256, 2)
void fattn_kernel(const bf16* __restrict__ q, const bf16* __restrict__ kv,
                  const bf16* __restrict__ kpe, bf16* __restrict__ attn) {
    const int qt = gridDim.x - 1 - blockIdx.x;
    const int h = blockIdx.y;
    const int q0 = qt * 64;
    const int tid = threadIdx.x;
    const int w = tid >> 6;
    const int l = tid & 63;
    const int lg = l >> 4;
    const int ln = l & 15;

    __shared__ __align__(16) short Ks[64][200];
    __shared__ __align__(16) short Vt[128][72];
    __shared__ __align__(16) short Pb[64][70];

    short8 qf[6];
    const short* qrow = (const short*)(q + (size_t)(q0 + w * 16 + ln) * (NHEAD * DQK) + h * DQK);
#pragma unroll
    for (int ks = 0; ks < 6; ++ks)
        qf[ks] = *(const short8*)(qrow + ks * 32 + lg * 8);

    f32x4 O[8];
#pragma unroll
    for (int ct = 0; ct < 8; ++ct) O[ct] = (f32x4){0.f, 0.f, 0.f, 0.f};
    float m_[4] = {-1e30f, -1e30f, -1e30f, -1e30f};
    float l_[4] = {0.f, 0.f, 0.f, 0.f};
    const float scale = 0.07216878364870322f;  // 192^-0.5

    const int dv = tid & 127;
    const int o0 = tid >> 7;

    // ---- prefetch registers ----
    uint4 rK[4], rR[2];
    short rV[4][8];
    auto load_tile = [&](int kk) {
#pragma unroll
        for (int p = 0; p < 4; ++p) {
            int cid = tid + p * 256;
            int r = cid >> 4;
            int d = (cid & 15) * 8;
            rK[p] = *(const uint4*)(kv + (size_t)(kk + r) * (NHEAD * (DNOPE + DV)) +
                                    h * (DNOPE + DV) + d);
        }
#pragma unroll
        for (int p = 0; p < 2; ++p) {
            int cid = tid + p * 256;
            int r = cid >> 3;
            int d = (cid & 7) * 8;
            rR[p] = *(const uint4*)(kpe + (size_t)(kk + r) * DROPE + d);
        }
#pragma unroll
        for (int p = 0; p < 4; ++p) {
            int o = o0 + 2 * p;
#pragma unroll
            for (int j = 0; j < 8; ++j)
                rV[p][j] = *(const short*)(kv + (size_t)(kk + o * 8 + j) * (NHEAD * (DNOPE + DV)) +
                                           h * (DNOPE + DV) + DNOPE + dv);
        }
    };

    load_tile(0);

    for (int k0 = 0; k0 <= q0; k0 += 64) {
        __syncthreads();  // previous tile's LDS reads complete
        // ---- registers -> LDS (same layout as verified staging) ----
#pragma unroll
        for (int p = 0; p < 4; ++p) {
            int cid = tid + p * 256;
            int r = cid >> 4;
            int d = (cid & 15) * 8;
            *(uint4*)&Ks[r][d] = rK[p];
        }
#pragma unroll
        for (int p = 0; p < 2; ++p) {
            int cid = tid + p * 256;
            int r = cid >> 3;
            int d = (cid & 7) * 8;
            *(uint4*)&Ks[r][128 + d] = rR[p];
        }
#pragma unroll
        for (int p = 0; p < 4; ++p) {
            int o = o0 + 2 * p;
            *(short8*)&Vt[dv][o * 8] = *(short8*)rV[p];
        }
        __syncthreads();
        // ---- fire next tile's loads; they complete under this tile's compute ----
        if (k0 + 64 <= q0) load_tile(k0 + 64);

        f32x4 S[4];
#pragma unroll
        for (int c = 0; c < 4; ++c) S[c] = (f32x4){0.f, 0.f, 0.f, 0.f};
#pragma unroll
        for (int ks = 0; ks < 6; ++ks) {
#pragma unroll
            for (int c = 0; c < 4; ++c) {
                short8 kf = *(const short8*)&Ks[c * 16 + ln][ks * 32 + lg * 8];
                S[c] = mfma16(qf[ks], kf, S[c]);
            }
        }

        const bool diag = (k0 == q0);
#pragma unroll
        for (int c = 0; c < 4; ++c) {
#pragma unroll
            for (int r = 0; r < 4; ++r) {
                float v = S[c][r] * scale;
                if (diag && (c * 16 + ln) > (w * 16 + lg * 4 + r)) v = -1e30f;
                S[c][r] = v;
            }
        }

        float alpha[4];
#pragma unroll
        for (int r = 0; r < 4; ++r) {
            float mx = fmaxf(fmaxf(S[0][r], S[1][r]), fmaxf(S[2][r], S[3][r]));
#pragma unroll
            for (int d = 1; d < 16; d <<= 1) mx = fmaxf(mx, __shfl_xor(mx, d));
            float mn = fmaxf(m_[r], mx);
            alpha[r] = __expf(m_[r] - mn);
            m_[r] = mn;
            float rs = 0.f;
#pragma unroll
            for (int c = 0; c < 4; ++c) {
                float p = __expf(S[c][r] - mn);
                S[c][r] = p;
                rs += p;
            }
#pragma unroll
            for (int d = 1; d < 16; d <<= 1) rs += __shfl_xor(rs, d);
            l_[r] = l_[r] * alpha[r] + rs;
        }
#pragma unroll
        for (int ct = 0; ct < 8; ++ct)
#pragma unroll
            for (int r = 0; r < 4; ++r) O[ct][r] *= alpha[r];

#pragma unroll
        for (int c = 0; c < 4; ++c)
#pragma unroll
            for (int r = 0; r < 4; ++r)
                Pb[w * 16 + lg * 4 + r][c * 16 + ln] = bf16bits(S[c][r]);

#pragma unroll
        for (int ks = 0; ks < 2; ++ks) {
            short8 pf = *(const short8*)&Pb[w * 16 + ln][ks * 32 + lg * 8];
#pragma unroll
            for (int ct = 0; ct < 8; ++ct) {
                short8 vf = *(const short8*)&Vt[ct * 16 + ln][ks * 32 + lg * 8];
                O[ct] = mfma16(pf, vf, O[ct]);
            }
        }
    }

#pragma unroll
    for (int r = 0; r < 4; ++r) {
        float inv = 1.f / l_[r];
        bf16* orow = attn + (size_t)(q0 + w * 16 + lg * 4 + r) * (NHEAD * DV) + h * DV;
#pragma unroll
        for (int ct = 0; ct < 8; ++ct)
            orow[ct * 16 + ln] = __float2bfloat16(O[ct][r] * inv);
    }
}

extern "C" void kernel_launch(void* const* d_in, const int* in_sizes, int n_in,
                              void* d_out, int out_size, void* d_ws, size_t ws_size,
                              hipStream_t stream) {
    const void* hidden = d_in[0];
    const void* cosb   = d_in[1];
    const void* sinb   = d_in[2];
    const void* w_qa   = d_in[3];
    const void* g_qa   = d_in[4];
    const void* w_qb   = d_in[5];
    const void* w_kva  = d_in[6];
    const void* g_kva  = d_in[7];
    const void* w_kvb  = d_in[8];
    const void* w_o    = d_in[9];

    // ws ~49.0 MB. Aliases into DEAD regions: attn->ws start; W01->kv; W23->q_a; W4->q.
    bf16* ws = (bf16*)d_ws;
    bf16* q_a  = ws;                                         // 2048*1536
    bf16* ckv  = q_a + (size_t)S_LEN * QLORA;                // 2048*640
    bf16* ckvn = ckv + (size_t)S_LEN * CKV_PAD;              // 2048*512
    bf16* q    = ckvn + (size_t)S_LEN * KVLORA;              // 2048*3072
    bf16* kv   = q + (size_t)S_LEN * NHEAD * DQK;            // 2048*4096
    bf16* kpe  = kv + (size_t)S_LEN * NHEAD * (DNOPE + DV);  // 2048*64
    bf16* hbf  = kpe + (size_t)S_LEN * DROPE;                // 2048*2048
    int* flag  = (int*)(hbf + (size_t)S_LEN * HID_D);
    bf16* attn = ws;
    bf16* W01  = kv;
    bf16* W23  = q_a;
    bf16* W4   = q;

    detect_kernel<<<1, 256, 0, stream>>>(hidden, flag);
    convert_kernel<<<(S_LEN * HID_D / 8 + 255) / 256, 256, 0, stream>>>(
        hidden, hbf, S_LEN * HID_D / 8, flag);

    // q_a = hidden @ w_qa ; rmsnorm in place
    transpose_kernel<<<dim3(QLORA / 64, HID_D / 64), 256, 0, stream>>>(
        w_qa, W01, HID_D, QLORA, QLORA, flag);
    mgemm_kernel<0><<<dim3(QLORA / 128, S_LEN / 128), 256, 0, stream>>>(
        hbf, W01, q_a, S_LEN, QLORA, HID_D, flag);
    rmsnorm_kernel<<<S_LEN, 256, 0, stream>>>(q_a, g_qa, q_a, QLORA, QLORA, QLORA, flag);
    // q = q_a @ w_qb
    transpose_kernel<<<dim3(NHEAD * DQK / 64, QLORA / 64), 256, 0, stream>>>(
        w_qb, W01, QLORA, NHEAD * DQK, NHEAD * DQK, flag);
    mgemm_kernel<0><<<dim3(NHEAD * DQK / 128, S_LEN / 128), 256, 0, stream>>>(
        q_a, W01, q, S_LEN, NHEAD * DQK, QLORA, flag);
    // ckv = hidden @ w_kva (N 576 -> 640 padded; pad cols zero)
    transpose_kernel<<<dim3(CKV_PAD / 64, HID_D / 64), 256, 0, stream>>>(
        w_kva, W23, HID_D, KVLORA + DROPE, CKV_PAD, flag);
    mgemm_kernel<0><<<dim3(CKV_PAD / 128, S_LEN / 128), 256, 0, stream>>>(
        hbf, W23, ckv, S_LEN, CKV_PAD, HID_D, flag);
    rmsnorm_kernel<<<S_LEN, 256, 0, stream>>>(ckv, g_kva, ckvn, KVLORA, CKV_PAD, KVLORA, flag);
    // kv = ckvn @ w_kvb
    transpose_kernel<<<dim3(NHEAD * (DNOPE + DV) / 64, KVLORA / 64), 256, 0, stream>>>(
        w_kvb, W23, KVLORA, NHEAD * (DNOPE + DV), NHEAD * (DNOPE + DV), flag);
    mgemm_kernel<0><<<dim3(NHEAD * (DNOPE + DV) / 128, S_LEN / 128), 256, 0, stream>>>(
        ckvn, W23, kv, S_LEN, NHEAD * (DNOPE + DV), KVLORA, flag);
    // rope + attention
    rope_kernel<<<S_LEN, 576, 0, stream>>>(q, ckv, kpe, cosb, sinb, flag);
    fattn_kernel<<<dim3(S_LEN / 64, NHEAD), 256, 0, stream>>>(q, kv, kpe, attn);
    // out = attn @ w_o ; d_out dtype per flag
    transpose_kernel<<<dim3(HID_D / 64, HID_D / 64), 256, 0, stream>>>(
        w_o, W4, HID_D, HID_D, HID_D, flag);
    mgemm_kernel<1><<<dim3(HID_D / 128, S_LEN / 128), 256, 0, stream>>>(
        attn, W4, d_out, S_LEN, HID_D, HID_D, flag);
}

// Round 10
// 438.185 us; speedup vs baseline: 1.2696x; 1.2696x over previous
//
#include <hip/hip_runtime.h>
#include <hip/hip_bf16.h>

#define S_LEN 2048
#define HID_D 2048
#define NHEAD 16
#define QLORA 1536
#define KVLORA 512
#define DNOPE 128
#define DROPE 64
#define DV 128
#define DQK 192
#define CKV_PAD 640  // KVLORA+DROPE (576) padded to x128

typedef __hip_bfloat16 bf16;
typedef __attribute__((ext_vector_type(8))) short short8;
typedef __attribute__((ext_vector_type(4))) float f32x4;

__device__ __forceinline__ float ldE(const float* p) { return *p; }
__device__ __forceinline__ float ldE(const bf16* p) { return __bfloat162float(*p); }
__device__ __forceinline__ void stE(float* p, float v) { *p = v; }
__device__ __forceinline__ void stE(bf16* p, float v) { *p = __float2bfloat16(v); }

__device__ __forceinline__ short bf16bits(float v) {
    __hip_bfloat16 h = __float2bfloat16(v);
    return *reinterpret_cast<short*>(&h);
}

__device__ __forceinline__ f32x4 mfma16(short8 a, short8 b, f32x4 c) {
    return __builtin_amdgcn_mfma_f32_16x16x32_bf16(a, b, c, 0, 0, 0);
}

// async global->LDS, 16B/lane. LDS dest = wave-uniform base + lane*16 (HW adds it).
__device__ __forceinline__ void gload16(const void* g, void* l) {
    __builtin_amdgcn_global_load_lds(
        (const __attribute__((address_space(1))) unsigned int*)g,
        (__attribute__((address_space(3))) unsigned int*)l, 16, 0, 0);
}

// Detect fp32 vs bf16 inputs by sniffing `hidden` as bf16 (parallel, 256 thr).
__global__ void detect_kernel(const void* hidden, int* flag) {
    __shared__ int red[256];
    const int tid = threadIdx.x;
    const bf16* hb = (const bf16*)hidden;
    float a = fabsf(__bfloat162float(hb[tid]));
    red[tid] = (!(a < 64.f) || (a != 0.f && a < 1e-30f)) ? 1 : 0;
    __syncthreads();
    for (int o = 128; o > 0; o >>= 1) {
        if (tid < o) red[tid] += red[tid + o];
        __syncthreads();
    }
    if (tid == 0) *flag = (red[0] > 16) ? 1 : 0;  // 1 => fp32
}

// out[i] = bf16(in[i]), 8 elems/thread.
__global__ void convert_kernel(const void* in, bf16* out, int n8, const int* flag) {
    int i = blockIdx.x * 256 + threadIdx.x;
    if (i >= n8) return;
    size_t off = (size_t)i * 8;
    short8 o;
    if (*flag) {
        const float* f = (const float*)in + off;
#pragma unroll
        for (int j = 0; j < 8; ++j) o[j] = bf16bits(f[j]);
    } else {
        o = *(const short8*)((const short*)in + off);
    }
    *(short8*)((short*)out + off) = o;
}

// out[Npad][K] (bf16) = in[K][N]^T, zero rows n>=N. K%64==0, N%64==0, Npad%64==0.
__global__ void transpose_kernel(const void* in, bf16* out, int K, int N, int Npad,
                                 const int* flag) {
    __shared__ __align__(16) short Ts[64][80];
    const int tid = threadIdx.x;
    const int n0 = blockIdx.x * 64, k0 = blockIdx.y * 64;
    const bool inb = n0 < N;  // tiles fully in or fully out (N%64==0)
    const int fp32 = *flag;
    const int kl = tid >> 4;
    const int nl = (tid & 15) * 4;
#pragma unroll
    for (int p = 0; p < 4; ++p) {
        int k = kl + p * 16;
        float v[4] = {0.f, 0.f, 0.f, 0.f};
        if (inb) {
            if (fp32) {
                const float4 f = *(const float4*)((const float*)in + (size_t)(k0 + k) * N + n0 + nl);
                v[0] = f.x; v[1] = f.y; v[2] = f.z; v[3] = f.w;
            } else {
                const bf16* bp = (const bf16*)in + (size_t)(k0 + k) * N + n0 + nl;
#pragma unroll
                for (int i = 0; i < 4; ++i) v[i] = __bfloat162float(bp[i]);
            }
        }
#pragma unroll
        for (int i = 0; i < 4; ++i) Ts[nl + i][k] = bf16bits(v[i]);
    }
    __syncthreads();
    const int nr = tid >> 2;
    const int kq = (tid & 3) * 16;
    short* op = (short*)out + (size_t)(n0 + nr) * K + k0 + kq;
    *(short8*)op = *(short8*)&Ts[nr][kq];
    *(short8*)(op + 8) = *(short8*)&Ts[nr][kq + 8];
}

// C[M][N] = A[M][K] @ Bt[N][K]^T, bf16 in, fp32 acc. 128x128 tile, BK=32,
// 4 waves 2x2, each 64x64 = 4x4 mfma_16x16x32. global_load_lds width-16 staging
// with k-quad XOR swizzle: frag ds_read_b128 conflict-free. (round-7 verified)
template <typename TC>
__device__ void mgemm_body(const bf16* __restrict__ A, const bf16* __restrict__ Bt,
                           TC* __restrict__ C, int M, int N, int K) {
    __shared__ __align__(16) short As[128 * 32];
    __shared__ __align__(16) short Bs[128 * 32];
    const int tid = threadIdx.x;
    const int w = tid >> 6, lane = tid & 63;
    const int lg = lane >> 4, ln = lane & 15;
    const int wm = w >> 1, wn = w & 1;
    const int m0 = blockIdx.y * 128, n0 = blockIdx.x * 128;

    const int c0 = w * 128 + lane, c1 = c0 + 64;
    const int r0 = c0 >> 2, kq0 = (c0 & 3) ^ ((r0 >> 1) & 3);
    const int r1 = c1 >> 2, kq1 = (c1 & 3) ^ ((r1 >> 1) & 3);
    const bf16* aP0 = A + (size_t)(m0 + r0) * K + kq0 * 8;
    const bf16* aP1 = A + (size_t)(m0 + r1) * K + kq1 * 8;
    const bf16* bP0 = Bt + (size_t)(n0 + r0) * K + kq0 * 8;
    const bf16* bP1 = Bt + (size_t)(n0 + r1) * K + kq1 * 8;
    short* aL0 = As + (size_t)(w * 128) * 8;
    short* aL1 = As + (size_t)(w * 128 + 64) * 8;
    short* bL0 = Bs + (size_t)(w * 128) * 8;
    short* bL1 = Bs + (size_t)(w * 128 + 64) * 8;

    const int sx = lg ^ ((ln >> 1) & 3);
    int aoff[4], boff[4];
#pragma unroll
    for (int i = 0; i < 4; ++i) {
        aoff[i] = (wm * 64 + i * 16 + ln) * 32 + sx * 8;
        boff[i] = (wn * 64 + i * 16 + ln) * 32 + sx * 8;
    }

    f32x4 acc[4][4];
#pragma unroll
    for (int i = 0; i < 4; ++i)
#pragma unroll
        for (int j = 0; j < 4; ++j) acc[i][j] = (f32x4){0.f, 0.f, 0.f, 0.f};

    for (int k0 = 0; k0 < K; k0 += 32) {
        __syncthreads();
        gload16(aP0 + k0, aL0);
        gload16(aP1 + k0, aL1);
        gload16(bP0 + k0, bL0);
        gload16(bP1 + k0, bL1);
        __syncthreads();
        short8 af[4], bfr[4];
#pragma unroll
        for (int i = 0; i < 4; ++i) af[i] = *(const short8*)&As[aoff[i]];
#pragma unroll
        for (int j = 0; j < 4; ++j) bfr[j] = *(const short8*)&Bs[boff[j]];
#pragma unroll
        for (int i = 0; i < 4; ++i)
#pragma unroll
            for (int j = 0; j < 4; ++j) acc[i][j] = mfma16(af[i], bfr[j], acc[i][j]);
    }
#pragma unroll
    for (int i = 0; i < 4; ++i)
#pragma unroll
        for (int j = 0; j < 4; ++j) {
            TC* cp = C + (size_t)(m0 + wm * 64 + i * 16 + lg * 4) * N + n0 + wn * 64 + j * 16 + ln;
#pragma unroll
            for (int r = 0; r < 4; ++r)
                stE(cp + (size_t)r * N, acc[i][j][r]);
        }
}

template <int FINAL>
__global__ __launch_bounds__(256, 2)
void mgemm_kernel(const bf16* A, const bf16* Bt, void* C, int M, int N, int K,
                  const int* flag) {
    if (FINAL && *flag) mgemm_body<float>(A, Bt, (float*)C, M, N, K);
    else                mgemm_body<bf16>(A, Bt, (bf16*)C, M, N, K);
}

template <typename TG>
__device__ void rmsnorm_body(const bf16* __restrict__ x, const TG* __restrict__ g,
                             bf16* __restrict__ y, int len, int xstride, int ystride) {
    const int s = blockIdx.x;
    const int tid = threadIdx.x;
    const bf16* xr = x + (size_t)s * xstride;
    float ss = 0.f;
    for (int i = tid; i < len; i += 256) {
        float v = __bfloat162float(xr[i]);
        ss += v * v;
    }
    __shared__ float red[256];
    red[tid] = ss;
    __syncthreads();
    for (int o = 128; o > 0; o >>= 1) {
        if (tid < o) red[tid] += red[tid + o];
        __syncthreads();
    }
    const float scale = rsqrtf(red[0] / (float)len + 1e-6f);
    bf16* yr = y + (size_t)s * ystride;
    for (int i = tid; i < len; i += 256)
        yr[i] = __float2bfloat16(__bfloat162float(xr[i]) * scale * ldE(&g[i]));
}

__global__ void rmsnorm_kernel(const bf16* x, const void* g, bf16* y,
                               int len, int xstride, int ystride, const int* flag) {
    if (*flag) rmsnorm_body<float>(x, (const float*)g, y, len, xstride, ystride);
    else       rmsnorm_body<bf16>(x, (const bf16*)g, y, len, xstride, ystride);
}

// RoPE (deinterleave form): out[p] = x[2p]*c - x[2p+1]*s; out[p+32] = x[2p+1]*c + x[2p]*s.
template <typename TG>
__device__ void rope_body(bf16* __restrict__ q, const bf16* __restrict__ ckv,
                          bf16* __restrict__ kpe, const TG* __restrict__ cosb,
                          const TG* __restrict__ sinb) {
    const int s = blockIdx.x;
    const int tid = threadIdx.x;  // blockDim = 576
    float x0 = 0.f, x1 = 0.f, c = 0.f, sn = 0.f;
    bf16* qbase = nullptr;
    int p = 0;
    const bool isq = tid < 512;
    const bool active = tid < 544;
    if (active) {
        if (isq) {
            const int h = tid >> 5;
            p = tid & 31;
            qbase = q + (size_t)s * (NHEAD * DQK) + h * DQK + DNOPE;
            x0 = __bfloat162float(qbase[2 * p]);
            x1 = __bfloat162float(qbase[2 * p + 1]);
        } else {
            p = tid - 512;
            const bf16* kb = ckv + (size_t)s * CKV_PAD + KVLORA;
            x0 = __bfloat162float(kb[2 * p]);
            x1 = __bfloat162float(kb[2 * p + 1]);
        }
        c = ldE(&cosb[s * 64 + p]);
        sn = ldE(&sinb[s * 64 + p]);
    }
    __syncthreads();
    if (active) {
        if (isq) {
            qbase[p] = __float2bfloat16(x0 * c - x1 * sn);
            qbase[p + 32] = __float2bfloat16(x1 * c + x0 * sn);
        } else {
            kpe[s * 64 + p] = __float2bfloat16(x0 * c - x1 * sn);
            kpe[s * 64 + p + 32] = __float2bfloat16(x1 * c + x0 * sn);
        }
    }
}

__global__ void rope_kernel(bf16* q, const bf16* ckv, bf16* kpe,
                            const void* cosb, const void* sinb, const int* flag) {
    if (*flag) rope_body<float>(q, ckv, kpe, (const float*)cosb, (const float*)sinb);
    else       rope_body<bf16>(q, ckv, kpe, (const bf16*)cosb, (const bf16*)sinb);
}

// Flash-style MFMA attention with SPLIT-K over key tiles (flash-decoding style).
// blockIdx.x in [0,48): bx<32 -> half-range partial blocks of qt=31-(bx>>1)
// (heavy, dispatched first); bx>=32 -> full-range blocks of qt=47-bx (<=16 tiles).
// Partial blocks write unnormalized O (bf16) + per-row m,l; reduce_kernel merges.
// Per-wave math identical to round-7-verified version.
__global__ __launch_bounds__(256, 2)
void fattn_kernel(const bf16* __restrict__ q, const bf16* __restrict__ kv,
                  const bf16* __restrict__ kpe, bf16* __restrict__ attn,
                  bf16* __restrict__ Opart, float* __restrict__ ml) {
    const int bx = blockIdx.x;
    const int h = blockIdx.y;
    int qt, t0, t1, pi;
    bool partial;
    if (bx < 32) {  // split halves of qt 16..31, heavy first
        partial = true;
        qt = 31 - (bx >> 1);
        const int half = bx & 1;
        const int nt = qt + 1, nh = (nt + 1) >> 1;
        t0 = half ? nh : 0;
        t1 = half ? nt : nh;
        pi = (qt - 16) * 2 + half;  // 0..31
    } else {        // full range, qt 15..0
        partial = false;
        qt = 47 - bx;
        t0 = 0;
        t1 = qt + 1;
        pi = 0;
    }
    const int q0 = qt * 64;
    const int tid = threadIdx.x;
    const int w = tid >> 6;
    const int l = tid & 63;
    const int lg = l >> 4;
    const int ln = l & 15;

    __shared__ __align__(16) short Ks[64][200];
    __shared__ __align__(16) short Vt[128][72];
    __shared__ __align__(16) short Pb[64][70];

    short8 qf[6];
    const short* qrow = (const short*)(q + (size_t)(q0 + w * 16 + ln) * (NHEAD * DQK) + h * DQK);
#pragma unroll
    for (int ks = 0; ks < 6; ++ks)
        qf[ks] = *(const short8*)(qrow + ks * 32 + lg * 8);

    f32x4 O[8];
#pragma unroll
    for (int ct = 0; ct < 8; ++ct) O[ct] = (f32x4){0.f, 0.f, 0.f, 0.f};
    float m_[4] = {-1e30f, -1e30f, -1e30f, -1e30f};
    float l_[4] = {0.f, 0.f, 0.f, 0.f};
    const float scale = 0.07216878364870322f;  // 192^-0.5

    for (int t = t0; t < t1; ++t) {
        const int k0 = t * 64;
#pragma unroll
        for (int p = 0; p < 4; ++p) {
            int cid = tid + p * 256;
            int r = cid >> 4;
            int d = (cid & 15) * 8;
            *(uint4*)&Ks[r][d] =
                *(const uint4*)(kv + (size_t)(k0 + r) * (NHEAD * (DNOPE + DV)) + h * (DNOPE + DV) + d);
        }
#pragma unroll
        for (int p = 0; p < 2; ++p) {
            int cid = tid + p * 256;
            int r = cid >> 3;
            int d = (cid & 7) * 8;
            *(uint4*)&Ks[r][128 + d] = *(const uint4*)(kpe + (size_t)(k0 + r) * DROPE + d);
        }
        {
            int dv = tid & 127;
            int o0 = tid >> 7;
#pragma unroll
            for (int p = 0; p < 4; ++p) {
                int o = o0 + 2 * p;
                short tmp[8];
#pragma unroll
                for (int j = 0; j < 8; ++j)
                    tmp[j] = *(const short*)(kv + (size_t)(k0 + o * 8 + j) * (NHEAD * (DNOPE + DV)) +
                                             h * (DNOPE + DV) + DNOPE + dv);
                *(short8*)&Vt[dv][o * 8] = *(short8*)tmp;
            }
        }
        __syncthreads();

        f32x4 S[4];
#pragma unroll
        for (int c = 0; c < 4; ++c) S[c] = (f32x4){0.f, 0.f, 0.f, 0.f};
#pragma unroll
        for (int ks = 0; ks < 6; ++ks) {
#pragma unroll
            for (int c = 0; c < 4; ++c) {
                short8 kf = *(const short8*)&Ks[c * 16 + ln][ks * 32 + lg * 8];
                S[c] = mfma16(qf[ks], kf, S[c]);
            }
        }

        const bool diag = (k0 == q0);
#pragma unroll
        for (int c = 0; c < 4; ++c) {
#pragma unroll
            for (int r = 0; r < 4; ++r) {
                float v = S[c][r] * scale;
                if (diag && (c * 16 + ln) > (w * 16 + lg * 4 + r)) v = -1e30f;
                S[c][r] = v;
            }
        }

        float alpha[4];
#pragma unroll
        for (int r = 0; r < 4; ++r) {
            float mx = fmaxf(fmaxf(S[0][r], S[1][r]), fmaxf(S[2][r], S[3][r]));
#pragma unroll
            for (int d = 1; d < 16; d <<= 1) mx = fmaxf(mx, __shfl_xor(mx, d));
            float mn = fmaxf(m_[r], mx);
            alpha[r] = __expf(m_[r] - mn);
            m_[r] = mn;
            float rs = 0.f;
#pragma unroll
            for (int c = 0; c < 4; ++c) {
                float p = __expf(S[c][r] - mn);
                S[c][r] = p;
                rs += p;
            }
#pragma unroll
            for (int d = 1; d < 16; d <<= 1) rs += __shfl_xor(rs, d);
            l_[r] = l_[r] * alpha[r] + rs;
        }
#pragma unroll
        for (int ct = 0; ct < 8; ++ct)
#pragma unroll
            for (int r = 0; r < 4; ++r) O[ct][r] *= alpha[r];

#pragma unroll
        for (int c = 0; c < 4; ++c)
#pragma unroll
            for (int r = 0; r < 4; ++r)
                Pb[w * 16 + lg * 4 + r][c * 16 + ln] = bf16bits(S[c][r]);

#pragma unroll
        for (int ks = 0; ks < 2; ++ks) {
            short8 pf = *(const short8*)&Pb[w * 16 + ln][ks * 32 + lg * 8];
#pragma unroll
            for (int ct = 0; ct < 8; ++ct) {
                short8 vf = *(const short8*)&Vt[ct * 16 + ln][ks * 32 + lg * 8];
                O[ct] = mfma16(pf, vf, O[ct]);
            }
        }
        __syncthreads();
    }

    if (!partial) {
#pragma unroll
        for (int r = 0; r < 4; ++r) {
            float inv = 1.f / l_[r];
            bf16* orow = attn + (size_t)(q0 + w * 16 + lg * 4 + r) * (NHEAD * DV) + h * DV;
#pragma unroll
            for (int ct = 0; ct < 8; ++ct)
                orow[ct * 16 + ln] = __float2bfloat16(O[ct][r] * inv);
        }
    } else {
        bf16* op = Opart + ((size_t)(h * 32 + pi) * 64 * DV);
        float* mlp = ml + ((size_t)(h * 32 + pi) * 64) * 2;
#pragma unroll
        for (int r = 0; r < 4; ++r) {
            const int rowloc = w * 16 + lg * 4 + r;
#pragma unroll
            for (int ct = 0; ct < 8; ++ct)
                op[(size_t)rowloc * DV + ct * 16 + ln] = __float2bfloat16(O[ct][r]);
            if (ln == 0) {
                mlp[rowloc * 2] = m_[r];
                mlp[rowloc * 2 + 1] = l_[r];
            }
        }
    }
}

// Merge the 2 partials for qt=16..31. grid (16, NHEAD), 256 thr.
__global__ void reduce_kernel(const bf16* __restrict__ Opart, const float* __restrict__ ml,
                              bf16* __restrict__ attn) {
    const int qq = blockIdx.x;        // qt = 16+qq
    const int h = blockIdx.y;
    const int tid = threadIdx.x;
    const int row = tid >> 2;         // 0..63
    const int d0 = (tid & 3) * 32;
    const int p1 = h * 32 + qq * 2, p2 = p1 + 1;
    const float m1 = ml[((size_t)p1 * 64 + row) * 2], l1 = ml[((size_t)p1 * 64 + row) * 2 + 1];
    const float m2 = ml[((size_t)p2 * 64 + row) * 2], l2 = ml[((size_t)p2 * 64 + row) * 2 + 1];
    const float m = fmaxf(m1, m2);
    const float f1 = __expf(m1 - m), f2 = __expf(m2 - m);
    const float inv = 1.f / (f1 * l1 + f2 * l2);
    const bf16* o1 = Opart + ((size_t)p1 * 64 + row) * DV + d0;
    const bf16* o2 = Opart + ((size_t)p2 * 64 + row) * DV + d0;
    bf16* orow = attn + (size_t)((16 + qq) * 64 + row) * (NHEAD * DV) + h * DV + d0;
#pragma unroll
    for (int j = 0; j < 32; ++j) {
        float v = f1 * __bfloat162float(o1[j]) + f2 * __bfloat162float(o2[j]);
        orow[j] = __float2bfloat16(v * inv);
    }
}

extern "C" void kernel_launch(void* const* d_in, const int* in_sizes, int n_in,
                              void* d_out, int out_size, void* d_ws, size_t ws_size,
                              hipStream_t stream) {
    const void* hidden = d_in[0];
    const void* cosb   = d_in[1];
    const void* sinb   = d_in[2];
    const void* w_qa   = d_in[3];
    const void* g_qa   = d_in[4];
    const void* w_qb   = d_in[5];
    const void* w_kva  = d_in[6];
    const void* g_kva  = d_in[7];
    const void* w_kvb  = d_in[8];
    const void* w_o    = d_in[9];

    // ws ~49.0 MB (proven). Liveness-audited aliases:
    //   attn (4.19M el) -> ws start (q_a/ckv/ckvn dead at fattn time)
    //   ml   (131K el as fp32) -> region0 slack after attn (5.50M total)
    //   Opart (4.19M el) -> hbf region (dead after kv mgemm)
    //   W01->kv, W23->q_a, W4->q (as before)
    bf16* ws = (bf16*)d_ws;
    bf16* q_a  = ws;                                         // 2048*1536
    bf16* ckv  = q_a + (size_t)S_LEN * QLORA;                // 2048*640
    bf16* ckvn = ckv + (size_t)S_LEN * CKV_PAD;              // 2048*512
    bf16* q    = ckvn + (size_t)S_LEN * KVLORA;              // 2048*3072
    bf16* kv   = q + (size_t)S_LEN * NHEAD * DQK;            // 2048*4096
    bf16* kpe  = kv + (size_t)S_LEN * NHEAD * (DNOPE + DV);  // 2048*64
    bf16* hbf  = kpe + (size_t)S_LEN * DROPE;                // 2048*2048
    int* flag  = (int*)(hbf + (size_t)S_LEN * HID_D);
    bf16* attn = ws;
    float* ml  = (float*)(ws + (size_t)S_LEN * HID_D);       // 256KB in region0 slack
    bf16* Opart = hbf;                                       // 512*64*128 bf16 = 8.39MB
    bf16* W01  = kv;
    bf16* W23  = q_a;
    bf16* W4   = q;

    detect_kernel<<<1, 256, 0, stream>>>(hidden, flag);
    convert_kernel<<<(S_LEN * HID_D / 8 + 255) / 256, 256, 0, stream>>>(
        hidden, hbf, S_LEN * HID_D / 8, flag);

    // q_a = hidden @ w_qa ; rmsnorm in place
    transpose_kernel<<<dim3(QLORA / 64, HID_D / 64), 256, 0, stream>>>(
        w_qa, W01, HID_D, QLORA, QLORA, flag);
    mgemm_kernel<0><<<dim3(QLORA / 128, S_LEN / 128), 256, 0, stream>>>(
        hbf, W01, q_a, S_LEN, QLORA, HID_D, flag);
    rmsnorm_kernel<<<S_LEN, 256, 0, stream>>>(q_a, g_qa, q_a, QLORA, QLORA, QLORA, flag);
    // q = q_a @ w_qb
    transpose_kernel<<<dim3(NHEAD * DQK / 64, QLORA / 64), 256, 0, stream>>>(
        w_qb, W01, QLORA, NHEAD * DQK, NHEAD * DQK, flag);
    mgemm_kernel<0><<<dim3(NHEAD * DQK / 128, S_LEN / 128), 256, 0, stream>>>(
        q_a, W01, q, S_LEN, NHEAD * DQK, QLORA, flag);
    // ckv = hidden @ w_kva (N 576 -> 640 padded; pad cols zero)
    transpose_kernel<<<dim3(CKV_PAD / 64, HID_D / 64), 256, 0, stream>>>(
        w_kva, W23, HID_D, KVLORA + DROPE, CKV_PAD, flag);
    mgemm_kernel<0><<<dim3(CKV_PAD / 128, S_LEN / 128), 256, 0, stream>>>(
        hbf, W23, ckv, S_LEN, CKV_PAD, HID_D, flag);
    rmsnorm_kernel<<<S_LEN, 256, 0, stream>>>(ckv, g_kva, ckvn, KVLORA, CKV_PAD, KVLORA, flag);
    // kv = ckvn @ w_kvb  (last reader of hbf is the ckv mgemm above)
    transpose_kernel<<<dim3(NHEAD * (DNOPE + DV) / 64, KVLORA / 64), 256, 0, stream>>>(
        w_kvb, W23, KVLORA, NHEAD * (DNOPE + DV), NHEAD * (DNOPE + DV), flag);
    mgemm_kernel<0><<<dim3(NHEAD * (DNOPE + DV) / 128, S_LEN / 128), 256, 0, stream>>>(
        ckvn, W23, kv, S_LEN, NHEAD * (DNOPE + DV), KVLORA, flag);
    // rope + attention (split-K) + merge
    rope_kernel<<<S_LEN, 576, 0, stream>>>(q, ckv, kpe, cosb, sinb, flag);
    fattn_kernel<<<dim3(48, NHEAD), 256, 0, stream>>>(q, kv, kpe, attn, Opart, ml);
    reduce_kernel<<<dim3(16, NHEAD), 256, 0, stream>>>(Opart, ml, attn);
    // out = attn @ w_o ; d_out dtype per flag
    transpose_kernel<<<dim3(HID_D / 64, HID_D / 64), 256, 0, stream>>>(
        w_o, W4, HID_D, HID_D, HID_D, flag);
    mgemm_kernel<1><<<dim3(HID_D / 128, S_LEN / 128), 256, 0, stream>>>(
        attn, W4, d_out, S_LEN, HID_D, HID_D, flag);
}